// Round 13
// baseline (245.172 us; speedup 1.0000x reference)
//
#include <hip/hip_runtime.h>
#include <hip/hip_bf16.h>

#define HH 32
#define DD 128
#define HD (HH*DD)          // 4096
#define NFILL 2048
#define FLEN 512
#define SCALE_F 0.08838834764831845f
#define NEGINF (-1e30f)
#define PSTRIDE 136         // floats per partial record: [m, l, pad..., acc[128]]

typedef short bf16x8 __attribute__((ext_vector_type(8)));
typedef float f32x4 __attribute__((ext_vector_type(4)));

__device__ __forceinline__ short f2bf(float x) {
    union { float f; unsigned u; } c; c.f = x;
    unsigned u = c.u;
    u += 0x7FFFu + ((u >> 16) & 1u);   // RNE
    return (short)(u >> 16);
}

__device__ __forceinline__ bf16x8 load8_bf16(const float* __restrict__ p) {
    float4 a = *(const float4*)p;
    float4 b = *(const float4*)(p + 4);
    bf16x8 r;
    r[0]=f2bf(a.x); r[1]=f2bf(a.y); r[2]=f2bf(a.z); r[3]=f2bf(a.w);
    r[4]=f2bf(b.x); r[5]=f2bf(b.y); r[6]=f2bf(b.z); r[7]=f2bf(b.w);
    return r;
}

// ---------------- gen inner-loop macros (depth-2 pipeline) ----------------
#define LOADPOS(S, i) do { \
    const float* _kb = ((i) < 16) ? (kb0 + (long)(i) * HD) : (kb1 + (long)((i) - 16) * HD); \
    const float* _vb = ((i) < 16) ? (vb0 + (long)(i) * HD) : (vb1 + (long)((i) - 16) * HD); \
    S##k0 = *(const float4*)_kb;        S##k1 = *(const float4*)(_kb + 4); \
    S##k2 = *(const float4*)(_kb + 8);  S##k3 = *(const float4*)(_kb + 12); \
    S##v0 = *(const float4*)_vb;        S##v1 = *(const float4*)(_vb + 4); \
    S##v2 = *(const float4*)(_vb + 8);  S##v3 = *(const float4*)(_vb + 12); \
} while (0)

#define COMPUTEPOS(S, i) do { \
    float dot = S##k0.x*qv[0]  + S##k0.y*qv[1]  + S##k0.z*qv[2]  + S##k0.w*qv[3] \
              + S##k1.x*qv[4]  + S##k1.y*qv[5]  + S##k1.z*qv[6]  + S##k1.w*qv[7] \
              + S##k2.x*qv[8]  + S##k2.y*qv[9]  + S##k2.z*qv[10] + S##k2.w*qv[11] \
              + S##k3.x*qv[12] + S##k3.y*qv[13] + S##k3.z*qv[14] + S##k3.w*qv[15]; \
    dot += __shfl_xor(dot, 1); \
    dot += __shfl_xor(dot, 2); \
    dot += __shfl_xor(dot, 4); \
    float s = dot * SCALE_F; \
    if (p0 + (i) == ctxm1) s = NEGINF;   /* stale slot: mask (wave-uniform) */ \
    const float mn = fmaxf(m, s); \
    const float sc = __expf(m - mn); \
    const float pw = __expf(s - mn); \
    lsum = lsum * sc + pw; \
    o[0]  = o[0]*sc  + pw*S##v0.x;  o[1]  = o[1]*sc  + pw*S##v0.y; \
    o[2]  = o[2]*sc  + pw*S##v0.z;  o[3]  = o[3]*sc  + pw*S##v0.w; \
    o[4]  = o[4]*sc  + pw*S##v1.x;  o[5]  = o[5]*sc  + pw*S##v1.y; \
    o[6]  = o[6]*sc  + pw*S##v1.z;  o[7]  = o[7]*sc  + pw*S##v1.w; \
    o[8]  = o[8]*sc  + pw*S##v2.x;  o[9]  = o[9]*sc  + pw*S##v2.y; \
    o[10] = o[10]*sc + pw*S##v2.z;  o[11] = o[11]*sc + pw*S##v2.w; \
    o[12] = o[12]*sc + pw*S##v3.x;  o[13] = o[13]*sc + pw*S##v3.y; \
    o[14] = o[14]*sc + pw*S##v3.z;  o[15] = o[15]*sc + pw*S##v3.w; \
    m = mn; \
} while (0)

#define SBAR __builtin_amdgcn_sched_barrier(0)

// ---------------- fill helpers (r9 known-good) ----------------
struct QS {
    bf16x8 qf[4];
    float  mrow[4], lsum[4];
    f32x4  o[8];
};

__device__ __forceinline__ void qs_init(QS& S, const float* qbase, int g16) {
    #pragma unroll
    for (int c = 0; c < 4; ++c) S.qf[c] = load8_bf16(qbase + c * 32 + g16 * 8);
    #pragma unroll
    for (int r = 0; r < 4; ++r) { S.mrow[r] = NEGINF; S.lsum[r] = 0.f; }
    #pragma unroll
    for (int n = 0; n < 8; ++n) { S.o[n][0]=0.f; S.o[n][1]=0.f; S.o[n][2]=0.f; S.o[n][3]=0.f; }
}

__device__ __forceinline__ void qs_tile(QS& S, int qt, int k0,
                                        const char* Kl, const char* Vt2,
                                        char* pbase, int g16, int li) {
    f32x4 sA; sA[0]=0.f; sA[1]=0.f; sA[2]=0.f; sA[3]=0.f;
    f32x4 sB; sB[0]=0.f; sB[1]=0.f; sB[2]=0.f; sB[3]=0.f;
    #pragma unroll
    for (int c = 0; c < 4; ++c) {
        const int rA = li, rB = li + 16;
        bf16x8 kfA = *(const bf16x8*)(Kl + ((rA * 256 + c * 64 + g16 * 16) ^ ((rA & 7) << 4)));
        bf16x8 kfB = *(const bf16x8*)(Kl + ((rB * 256 + c * 64 + g16 * 16) ^ ((rB & 7) << 4)));
        sA = __builtin_amdgcn_mfma_f32_16x16x32_bf16(S.qf[c], kfA, sA, 0, 0, 0);
        sB = __builtin_amdgcn_mfma_f32_16x16x32_bf16(S.qf[c], kfB, sB, 0, 0, 0);
    }
    float pA[4], pB[4], corr[4];
    #pragma unroll
    for (int r = 0; r < 4; ++r) {
        const int qrow = qt * 16 + g16 * 4 + r;
        float a  = (k0 + li      <= qrow) ? sA[r] * SCALE_F : NEGINF;
        float bb = (k0 + 16 + li <= qrow) ? sB[r] * SCALE_F : NEGINF;
        float rm = fmaxf(a, bb);
        #pragma unroll
        for (int off = 1; off < 16; off <<= 1) rm = fmaxf(rm, __shfl_xor(rm, off));
        const float mn = fmaxf(S.mrow[r], rm);
        corr[r] = __expf(S.mrow[r] - mn);
        pA[r] = __expf(a  - mn);
        pB[r] = __expf(bb - mn);
        float rs = pA[r] + pB[r];
        #pragma unroll
        for (int off = 1; off < 16; off <<= 1) rs += __shfl_xor(rs, off);
        S.lsum[r] = S.lsum[r] * corr[r] + rs;
        S.mrow[r] = mn;
    }
    #pragma unroll
    for (int n = 0; n < 8; ++n)
        #pragma unroll
        for (int r = 0; r < 4; ++r) S.o[n][r] *= corr[r];

    #pragma unroll
    for (int r = 0; r < 4; ++r) {
        const int row = g16 * 4 + r;
        const int xo  = (row & 3) << 4;
        *(short*)(pbase + ((row * 64 + li * 2     ) ^ xo)) = f2bf(pA[r]);
        *(short*)(pbase + ((row * 64 + 32 + li * 2) ^ xo)) = f2bf(pB[r]);
    }
    asm volatile("s_waitcnt lgkmcnt(0)" ::: "memory");
    __builtin_amdgcn_sched_barrier(0);
    bf16x8 pa = *(const bf16x8*)(pbase + ((li * 64 + g16 * 16) ^ ((li & 3) << 4)));

    #pragma unroll
    for (int n = 0; n < 8; ++n) {
        bf16x8 vf = *(const bf16x8*)(Vt2 + (n * 1024 + g16 * 256 + li * 16));
        S.o[n] = __builtin_amdgcn_mfma_f32_16x16x32_bf16(pa, vf, S.o[n], 0, 0, 0);
    }
}

__device__ __forceinline__ void qs_out(QS& S, int qt, int b, int h, int g16, int li,
                                       float* __restrict__ out) {
    float inv[4];
    #pragma unroll
    for (int r = 0; r < 4; ++r) inv[r] = 1.f / S.lsum[r];
    #pragma unroll
    for (int n = 0; n < 8; ++n) {
        #pragma unroll
        for (int r = 0; r < 4; ++r) {
            const int t = b * FLEN + qt * 16 + g16 * 4 + r;
            out[(long)t * 4096 + h * DD + n * 16 + li] = S.o[n][r] * inv[r];
        }
    }
}

// ======================= FUSED: fill (blocks 0..255) + gen (blocks 256..511) =======================
// 512 blocks x 512 thr, __launch_bounds__(512,4) -> VGPR<=128, 2 blocks/CU co-resident.
// Dispatch: one fill block per CU first, then one gen block per CU -> heterogeneous
// co-residency with INDEPENDENT per-block barriers. Fill's MFMA/LDS work overlaps
// gen's HBM streaming; after fill drains, gen runs alone at 8 waves/CU.
__global__ __launch_bounds__(512, 4)
void fused_kernel(const float* __restrict__ q, const float* __restrict__ k,
                  const float* __restrict__ v, const float* __restrict__ kc,
                  const float* __restrict__ vc, const int* __restrict__ btab,
                  const int* __restrict__ ctxlens, float* __restrict__ ws,
                  float* __restrict__ out)
{
    __shared__ union {
        struct {                       // gen: 2 units of 4 waves
            float marr[2][4][8];
            float larr[2][4][8];
            float accs[2][4][1024];    // 32 KB
        } g;
        struct {                       // fill
            short Kl[32 * 128];        // 8 KB
            short Vt2[8 * 4 * 16 * 8]; // 8 KB
            short plds[8][16][32];     // 8 KB
        } f;
    } sm;

    const int bid  = blockIdx.x;
    const int tid  = threadIdx.x;
    const int wv   = tid >> 6;
    const int lane = tid & 63;
    const int g16  = lane >> 4;
    const int li   = lane & 15;

    if (bid >= 256) {
        // ============================ GEN ============================
        const int unit = wv >> 2;            // 0/1
        const int wv4  = wv & 3;
        const int gid  = (bid - 256) * 2 + unit;   // 0..511
        const int g    = gid >> 5;
        const int hg   = (gid >> 3) & 3;
        const int pc   = gid & 7;
        const int hl   = lane >> 3;
        const int ctx  = ctxlens[g];
        const int ctxm1 = ctx - 1;
        const int p0   = pc * 128 + wv4 * 32;

        const long blk0 = btab[g * 64 + (p0 >> 4)];
        const long blk1 = btab[g * 64 + (p0 >> 4) + 1];
        const long off  = hg * 1024 + lane * 16;
        const float* kb0 = kc + blk0 * 16 * HD + off;
        const float* vb0 = vc + blk0 * 16 * HD + off;
        const float* kb1 = kc + blk1 * 16 * HD + off;
        const float* vb1 = vc + blk1 * 16 * HD + off;

        const long freshoff = (long)(NFILL + g) * HD + off;
        float qv[16];
        {
            const float* qp = q + freshoff;
            float4 a0 = *(const float4*)qp,       a1 = *(const float4*)(qp + 4);
            float4 a2 = *(const float4*)(qp + 8), a3 = *(const float4*)(qp + 12);
            qv[0]=a0.x; qv[1]=a0.y; qv[2]=a0.z;  qv[3]=a0.w;
            qv[4]=a1.x; qv[5]=a1.y; qv[6]=a1.z;  qv[7]=a1.w;
            qv[8]=a2.x; qv[9]=a2.y; qv[10]=a2.z; qv[11]=a2.w;
            qv[12]=a3.x; qv[13]=a3.y; qv[14]=a3.z; qv[15]=a3.w;
        }

        float m = NEGINF, lsum = 0.f;
        float o[16];
        #pragma unroll
        for (int j = 0; j < 16; ++j) o[j] = 0.f;

        float4 Ak0,Ak1,Ak2,Ak3,Av0,Av1,Av2,Av3;
        float4 Bk0,Bk1,Bk2,Bk3,Bv0,Bv1,Bv2,Bv3;

        LOADPOS(A, 0); LOADPOS(B, 1); SBAR;
        #pragma unroll
        for (int i = 0; i < 32; i += 2) {
            COMPUTEPOS(A, i);
            if (i + 2 < 32) { LOADPOS(A, i + 2); } SBAR;
            COMPUTEPOS(B, i + 1);
            if (i + 3 < 32) { LOADPOS(B, i + 3); } SBAR;
        }

        // fresh token (position ctx-1) from k/v — wave-uniform, after the loop
        if (ctxm1 >= p0 && ctxm1 < p0 + 32) {
            const float* _kb = k + freshoff;
            const float* _vb = v + freshoff;
            float4 Fk0 = *(const float4*)_kb,       Fk1 = *(const float4*)(_kb + 4);
            float4 Fk2 = *(const float4*)(_kb + 8), Fk3 = *(const float4*)(_kb + 12);
            float4 Fv0 = *(const float4*)_vb,       Fv1 = *(const float4*)(_vb + 4);
            float4 Fv2 = *(const float4*)(_vb + 8), Fv3 = *(const float4*)(_vb + 12);
            float dot = Fk0.x*qv[0]  + Fk0.y*qv[1]  + Fk0.z*qv[2]  + Fk0.w*qv[3]
                      + Fk1.x*qv[4]  + Fk1.y*qv[5]  + Fk1.z*qv[6]  + Fk1.w*qv[7]
                      + Fk2.x*qv[8]  + Fk2.y*qv[9]  + Fk2.z*qv[10] + Fk2.w*qv[11]
                      + Fk3.x*qv[12] + Fk3.y*qv[13] + Fk3.z*qv[14] + Fk3.w*qv[15];
            dot += __shfl_xor(dot, 1);
            dot += __shfl_xor(dot, 2);
            dot += __shfl_xor(dot, 4);
            const float s  = dot * SCALE_F;
            const float mn = fmaxf(m, s);
            const float sc = __expf(m - mn);
            const float pw = __expf(s - mn);
            lsum = lsum * sc + pw;
            o[0]  = o[0]*sc  + pw*Fv0.x;  o[1]  = o[1]*sc  + pw*Fv0.y;
            o[2]  = o[2]*sc  + pw*Fv0.z;  o[3]  = o[3]*sc  + pw*Fv0.w;
            o[4]  = o[4]*sc  + pw*Fv1.x;  o[5]  = o[5]*sc  + pw*Fv1.y;
            o[6]  = o[6]*sc  + pw*Fv1.z;  o[7]  = o[7]*sc  + pw*Fv1.w;
            o[8]  = o[8]*sc  + pw*Fv2.x;  o[9]  = o[9]*sc  + pw*Fv2.y;
            o[10] = o[10]*sc + pw*Fv2.z;  o[11] = o[11]*sc + pw*Fv2.w;
            o[12] = o[12]*sc + pw*Fv3.x;  o[13] = o[13]*sc + pw*Fv3.y;
            o[14] = o[14]*sc + pw*Fv3.z;  o[15] = o[15]*sc + pw*Fv3.w;
            m = mn;
        }

        // ---- in-block merge: each unit's 4 waves ----
        #pragma unroll
        for (int j = 0; j < 16; ++j) sm.g.accs[unit][wv4][hl * 128 + (lane & 7) * 16 + j] = o[j];
        if ((lane & 7) == 0) { sm.g.marr[unit][wv4][hl] = m; sm.g.larr[unit][wv4][hl] = lsum; }
        __syncthreads();

        {
            const int u2  = tid >> 8;          // unit this thread reduces
            const int ut  = tid & 255;
            const int idx = ut * 4;            // 1024 entries = 8 heads x 128 d
            const int hh  = idx >> 7;
            const int dd  = idx & 127;
            const int gid2 = (bid - 256) * 2 + u2;
            const int g2  = gid2 >> 5;
            const int hg2 = (gid2 >> 3) & 3;
            const int pc2 = gid2 & 7;
            float M = NEGINF;
            #pragma unroll
            for (int w = 0; w < 4; ++w) M = fmaxf(M, sm.g.marr[u2][w][hh]);
            float L = 0.f, n0 = 0.f, n1 = 0.f, n2 = 0.f, n3 = 0.f;
            #pragma unroll
            for (int w = 0; w < 4; ++w) {
                const float e = __expf(sm.g.marr[u2][w][hh] - M);
                L  += e * sm.g.larr[u2][w][hh];
                n0 += e * sm.g.accs[u2][w][hh * 128 + dd];
                n1 += e * sm.g.accs[u2][w][hh * 128 + dd + 1];
                n2 += e * sm.g.accs[u2][w][hh * 128 + dd + 2];
                n3 += e * sm.g.accs[u2][w][hh * 128 + dd + 3];
            }
            const long base = ((long)(g2 * 32 + hg2 * 8 + hh) * 8 + pc2) * PSTRIDE;
            ws[base + 8 + dd]     = n0;
            ws[base + 8 + dd + 1] = n1;
            ws[base + 8 + dd + 2] = n2;
            ws[base + 8 + dd + 3] = n3;
            if (dd == 0) { ws[base] = M; ws[base + 1] = L; }
        }
    } else {
        // ============================ FILL (r9 body) ============================
        const int b   = bid >> 6;
        const int h   = (bid >> 1) & 31;
        const int jh  = bid & 1;

        const int qtA = 2 * wv + jh;
        const int qtB = qtA + 16;
        const int npA = wv + 1;
        const int npB = wv + 9;

        QS SA, SB2;
        qs_init(SA,  q + ((long)(b * FLEN + qtA * 16 + li) * HH + h) * DD, g16);
        qs_init(SB2, q + ((long)(b * FLEN + qtB * 16 + li) * HH + h) * DD, g16);

        const int spos = tid >> 4;
        const int sd8  = tid & 15;
        const int vd   = tid & 127;
        const int voct = tid >> 7;

        char* pbase = (char*)&sm.f.plds[wv][0][0];

        for (int kp = 0; kp < 16; ++kp) {
            const int k0 = kp * 32;
            {
                const float* src = k + ((long)(b * FLEN + k0 + spos) * HH + h) * DD + sd8 * 8;
                bf16x8 w = load8_bf16(src);
                const int base = spos * 256 + sd8 * 16;
                *(bf16x8*)((char*)sm.f.Kl + (base ^ ((spos & 7) << 4))) = w;
            }
            {
                const float* src = v + ((long)(b * FLEN + k0 + voct * 8) * HH + h) * DD + vd;
                bf16x8 w;
                #pragma unroll
                for (int jj = 0; jj < 8; ++jj)
                    w[jj] = f2bf(src[(long)jj * HD]);
                *(bf16x8*)((char*)sm.f.Vt2 + ((vd >> 4) * 1024 + voct * 256 + (vd & 15) * 16)) = w;
            }
            __syncthreads();

            if (kp < npA) qs_tile(SA,  qtA, k0, (const char*)sm.f.Kl, (const char*)sm.f.Vt2, pbase, g16, li);
            if (kp < npB) qs_tile(SB2, qtB, k0, (const char*)sm.f.Kl, (const char*)sm.f.Vt2, pbase, g16, li);

            __syncthreads();
        }

        qs_out(SA,  qtA, b, h, g16, li, out);
        qs_out(SB2, qtB, b, h, g16, li, out);
    }
}

// ======================= MERGE: 8 chunk-partials per (g,h) =======================
__global__ __launch_bounds__(256)
void merge_kernel(const float* __restrict__ ws, float* __restrict__ out)
{
    const int idx = blockIdx.x * 256 + threadIdx.x;   // 65536
    const int gh  = idx >> 7;       // 0..511
    const int d   = idx & 127;
    const int g   = gh >> 5;
    const int h   = gh & 31;
    float ms[8];
    float M = NEGINF;
    #pragma unroll
    for (int c = 0; c < 8; ++c) {
        ms[c] = ws[((long)gh * 8 + c) * PSTRIDE];
        M = fmaxf(M, ms[c]);
    }
    float L = 0.f, num = 0.f;
    #pragma unroll
    for (int c = 0; c < 8; ++c) {
        const long rec = ((long)gh * 8 + c) * PSTRIDE;
        const float e = __expf(ms[c] - M);
        L   += e * ws[rec + 1];
        num += e * ws[rec + 8 + d];
    }
    out[(long)(NFILL + g) * 4096 + h * DD + d] = num / L;
}

extern "C" void kernel_launch(void* const* d_in, const int* in_sizes, int n_in,
                              void* d_out, int out_size, void* d_ws, size_t ws_size,
                              hipStream_t stream) {
    const float* q  = (const float*)d_in[0];
    const float* k  = (const float*)d_in[1];
    const float* v  = (const float*)d_in[2];
    const float* kc = (const float*)d_in[3];
    const float* vc = (const float*)d_in[4];
    // d_in[5] = slot_mapping (derivable; caches are not outputs)
    const int* btab    = (const int*)d_in[6];
    const int* ctxlens = (const int*)d_in[7];
    float* outp = (float*)d_out;
    float* ws   = (float*)d_ws;   // 4096 partial records x 136 floats = 2.2 MB

    fused_kernel<<<dim3(512), dim3(512), 0, stream>>>(q, k, v, kc, vc, btab, ctxlens, ws, outp);
    merge_kernel<<<dim3(256), dim3(256), 0, stream>>>(ws, outp);
}

// Round 14
// 201.786 us; speedup vs baseline: 1.2150x; 1.2150x over previous
//
#include <hip/hip_runtime.h>
#include <hip/hip_bf16.h>

#define HH 32
#define DD 128
#define HD (HH*DD)          // 4096
#define NFILL 2048
#define FLEN 512
#define SCALE_F 0.08838834764831845f
#define NEGINF (-1e30f)
#define PSTRIDE 136         // floats per partial record: [m, l, pad..., acc[128]]

typedef short bf16x8 __attribute__((ext_vector_type(8)));
typedef float f32x4 __attribute__((ext_vector_type(4)));

__device__ __forceinline__ short f2bf(float x) {
    union { float f; unsigned u; } c; c.f = x;
    unsigned u = c.u;
    u += 0x7FFFu + ((u >> 16) & 1u);   // RNE
    return (short)(u >> 16);
}

__device__ __forceinline__ bf16x8 load8_bf16(const float* __restrict__ p) {
    float4 a = *(const float4*)p;
    float4 b = *(const float4*)(p + 4);
    bf16x8 r;
    r[0]=f2bf(a.x); r[1]=f2bf(a.y); r[2]=f2bf(a.z); r[3]=f2bf(a.w);
    r[4]=f2bf(b.x); r[5]=f2bf(b.y); r[6]=f2bf(b.z); r[7]=f2bf(b.w);
    return r;
}

// ======================= GEN v5: block-contiguous slot reads =======================
// 512 blocks x 256 thr: g=bid>>5, pc=bid&31 (32-position chunk). Wave wv = hg quarter.
// All 4 waves of a block walk the SAME 32 positions -> each slot's full 16KB K/V span
// is read contiguously & simultaneously by the block. No LDS, no __syncthreads:
// each wave writes its own 8-head partial (m,l,acc) record per (g,h,pc).
#define LOADPOS(S, i) do { \
    const float* _kb = ((i) < 16) ? (kb0 + (long)(i) * HD) : (kb1 + (long)((i) - 16) * HD); \
    const float* _vb = ((i) < 16) ? (vb0 + (long)(i) * HD) : (vb1 + (long)((i) - 16) * HD); \
    S##k0 = *(const float4*)_kb;        S##k1 = *(const float4*)(_kb + 4); \
    S##k2 = *(const float4*)(_kb + 8);  S##k3 = *(const float4*)(_kb + 12); \
    S##v0 = *(const float4*)_vb;        S##v1 = *(const float4*)(_vb + 4); \
    S##v2 = *(const float4*)(_vb + 8);  S##v3 = *(const float4*)(_vb + 12); \
} while (0)

#define COMPUTEPOS(S, i) do { \
    float dot = S##k0.x*qv[0]  + S##k0.y*qv[1]  + S##k0.z*qv[2]  + S##k0.w*qv[3] \
              + S##k1.x*qv[4]  + S##k1.y*qv[5]  + S##k1.z*qv[6]  + S##k1.w*qv[7] \
              + S##k2.x*qv[8]  + S##k2.y*qv[9]  + S##k2.z*qv[10] + S##k2.w*qv[11] \
              + S##k3.x*qv[12] + S##k3.y*qv[13] + S##k3.z*qv[14] + S##k3.w*qv[15]; \
    dot += __shfl_xor(dot, 1); \
    dot += __shfl_xor(dot, 2); \
    dot += __shfl_xor(dot, 4); \
    float s = dot * SCALE_F; \
    if (p0 + (i) == ctxm1) s = NEGINF;   /* stale slot: mask (wave-uniform) */ \
    const float mn = fmaxf(m, s); \
    const float sc = __expf(m - mn); \
    const float pw = __expf(s - mn); \
    lsum = lsum * sc + pw; \
    o[0]  = o[0]*sc  + pw*S##v0.x;  o[1]  = o[1]*sc  + pw*S##v0.y; \
    o[2]  = o[2]*sc  + pw*S##v0.z;  o[3]  = o[3]*sc  + pw*S##v0.w; \
    o[4]  = o[4]*sc  + pw*S##v1.x;  o[5]  = o[5]*sc  + pw*S##v1.y; \
    o[6]  = o[6]*sc  + pw*S##v1.z;  o[7]  = o[7]*sc  + pw*S##v1.w; \
    o[8]  = o[8]*sc  + pw*S##v2.x;  o[9]  = o[9]*sc  + pw*S##v2.y; \
    o[10] = o[10]*sc + pw*S##v2.z;  o[11] = o[11]*sc + pw*S##v2.w; \
    o[12] = o[12]*sc + pw*S##v3.x;  o[13] = o[13]*sc + pw*S##v3.y; \
    o[14] = o[14]*sc + pw*S##v3.z;  o[15] = o[15]*sc + pw*S##v3.w; \
    m = mn; \
} while (0)

#define SBAR __builtin_amdgcn_sched_barrier(0)

__global__ __launch_bounds__(256, 1)
void gen_kernel(const float* __restrict__ q, const float* __restrict__ k,
                const float* __restrict__ v, const float* __restrict__ kc,
                const float* __restrict__ vc, const int* __restrict__ btab,
                const int* __restrict__ ctxlens, float* __restrict__ ws)
{
    const int bid  = blockIdx.x;
    const int g    = bid >> 5;
    const int pc   = bid & 31;
    const int tid  = threadIdx.x;
    const int wv   = tid >> 6;       // = hg quarter
    const int lane = tid & 63;
    const int hl   = lane >> 3;      // head-in-group 0..7
    const int ctx  = ctxlens[g];
    const int ctxm1 = ctx - 1;
    const int p0   = pc * 32;

    const long blk0 = btab[g * 64 + (p0 >> 4)];
    const long blk1 = btab[g * 64 + (p0 >> 4) + 1];
    const long off  = wv * 1024 + lane * 16;   // head = wv*8 + hl, d = (lane&7)*16
    const float* kb0 = kc + blk0 * 16 * HD + off;
    const float* vb0 = vc + blk0 * 16 * HD + off;
    const float* kb1 = kc + blk1 * 16 * HD + off;
    const float* vb1 = vc + blk1 * 16 * HD + off;

    const long freshoff = (long)(NFILL + g) * HD + off;
    float qv[16];
    {
        const float* qp = q + freshoff;
        float4 a0 = *(const float4*)qp,       a1 = *(const float4*)(qp + 4);
        float4 a2 = *(const float4*)(qp + 8), a3 = *(const float4*)(qp + 12);
        qv[0]=a0.x; qv[1]=a0.y; qv[2]=a0.z;  qv[3]=a0.w;
        qv[4]=a1.x; qv[5]=a1.y; qv[6]=a1.z;  qv[7]=a1.w;
        qv[8]=a2.x; qv[9]=a2.y; qv[10]=a2.z; qv[11]=a2.w;
        qv[12]=a3.x; qv[13]=a3.y; qv[14]=a3.z; qv[15]=a3.w;
    }

    float m = NEGINF, lsum = 0.f;
    float o[16];
    #pragma unroll
    for (int j = 0; j < 16; ++j) o[j] = 0.f;

    float4 Ak0,Ak1,Ak2,Ak3,Av0,Av1,Av2,Av3;
    float4 Bk0,Bk1,Bk2,Bk3,Bv0,Bv1,Bv2,Bv3;

    LOADPOS(A, 0); LOADPOS(B, 1); SBAR;
    #pragma unroll
    for (int i = 0; i < 32; i += 2) {
        COMPUTEPOS(A, i);
        if (i + 2 < 32) { LOADPOS(A, i + 2); } SBAR;
        COMPUTEPOS(B, i + 1);
        if (i + 3 < 32) { LOADPOS(B, i + 3); } SBAR;
    }

    // fresh token (position ctx-1) from k/v — all waves of the owning block
    if (ctxm1 >= p0 && ctxm1 < p0 + 32) {
        const float* _kb = k + freshoff;
        const float* _vb = v + freshoff;
        float4 Fk0 = *(const float4*)_kb,       Fk1 = *(const float4*)(_kb + 4);
        float4 Fk2 = *(const float4*)(_kb + 8), Fk3 = *(const float4*)(_kb + 12);
        float4 Fv0 = *(const float4*)_vb,       Fv1 = *(const float4*)(_vb + 4);
        float4 Fv2 = *(const float4*)(_vb + 8), Fv3 = *(const float4*)(_vb + 12);
        float dot = Fk0.x*qv[0]  + Fk0.y*qv[1]  + Fk0.z*qv[2]  + Fk0.w*qv[3]
                  + Fk1.x*qv[4]  + Fk1.y*qv[5]  + Fk1.z*qv[6]  + Fk1.w*qv[7]
                  + Fk2.x*qv[8]  + Fk2.y*qv[9]  + Fk2.z*qv[10] + Fk2.w*qv[11]
                  + Fk3.x*qv[12] + Fk3.y*qv[13] + Fk3.z*qv[14] + Fk3.w*qv[15];
        dot += __shfl_xor(dot, 1);
        dot += __shfl_xor(dot, 2);
        dot += __shfl_xor(dot, 4);
        const float s  = dot * SCALE_F;
        const float mn = fmaxf(m, s);
        const float sc = __expf(m - mn);
        const float pw = __expf(s - mn);
        lsum = lsum * sc + pw;
        o[0]  = o[0]*sc  + pw*Fv0.x;  o[1]  = o[1]*sc  + pw*Fv0.y;
        o[2]  = o[2]*sc  + pw*Fv0.z;  o[3]  = o[3]*sc  + pw*Fv0.w;
        o[4]  = o[4]*sc  + pw*Fv1.x;  o[5]  = o[5]*sc  + pw*Fv1.y;
        o[6]  = o[6]*sc  + pw*Fv1.z;  o[7]  = o[7]*sc  + pw*Fv1.w;
        o[8]  = o[8]*sc  + pw*Fv2.x;  o[9]  = o[9]*sc  + pw*Fv2.y;
        o[10] = o[10]*sc + pw*Fv2.z;  o[11] = o[11]*sc + pw*Fv2.w;
        o[12] = o[12]*sc + pw*Fv3.x;  o[13] = o[13]*sc + pw*Fv3.y;
        o[14] = o[14]*sc + pw*Fv3.z;  o[15] = o[15]*sc + pw*Fv3.w;
        m = mn;
    }

    // ---- direct per-wave partial write: record (g, h = wv*8+hl, pc) ----
    {
        const int h   = wv * 8 + hl;
        const int dl  = (lane & 7) * 16;
        const long rec = ((long)(g * 32 + h) * 32 + pc) * PSTRIDE;
        #pragma unroll
        for (int t = 0; t < 4; ++t)
            *(float4*)(ws + rec + 8 + dl + 4 * t) = make_float4(o[4*t], o[4*t+1], o[4*t+2], o[4*t+3]);
        if ((lane & 7) == 0) { ws[rec] = m; ws[rec + 1] = lsum; }
    }
}

// ======================= MERGE: 32 chunk-partials per (g,h) =======================
__global__ __launch_bounds__(256)
void merge_kernel(const float* __restrict__ ws, float* __restrict__ out)
{
    const int idx = blockIdx.x * 256 + threadIdx.x;   // 65536
    const int gh  = idx >> 7;       // 0..511
    const int d   = idx & 127;
    const int g   = gh >> 5;
    const int h   = gh & 31;
    float M = NEGINF;
    #pragma unroll 8
    for (int c = 0; c < 32; ++c)
        M = fmaxf(M, ws[((long)gh * 32 + c) * PSTRIDE]);
    float L = 0.f, num = 0.f;
    #pragma unroll 8
    for (int c = 0; c < 32; ++c) {
        const long rec = ((long)gh * 32 + c) * PSTRIDE;
        const float e = __expf(ws[rec] - M);
        L   += e * ws[rec + 1];
        num += e * ws[rec + 8 + d];
    }
    out[(long)(NFILL + g) * 4096 + h * DD + d] = num / L;
}

// ======================= FILL v4 (r9 known-good, unchanged) =======================
struct QS {
    bf16x8 qf[4];
    float  mrow[4], lsum[4];
    f32x4  o[8];
};

__device__ __forceinline__ void qs_init(QS& S, const float* qbase, int g16) {
    #pragma unroll
    for (int c = 0; c < 4; ++c) S.qf[c] = load8_bf16(qbase + c * 32 + g16 * 8);
    #pragma unroll
    for (int r = 0; r < 4; ++r) { S.mrow[r] = NEGINF; S.lsum[r] = 0.f; }
    #pragma unroll
    for (int n = 0; n < 8; ++n) { S.o[n][0]=0.f; S.o[n][1]=0.f; S.o[n][2]=0.f; S.o[n][3]=0.f; }
}

__device__ __forceinline__ void qs_tile(QS& S, int qt, int k0,
                                        const char* Kl, const char* Vt2,
                                        char* pbase, int g16, int li) {
    f32x4 sA; sA[0]=0.f; sA[1]=0.f; sA[2]=0.f; sA[3]=0.f;
    f32x4 sB; sB[0]=0.f; sB[1]=0.f; sB[2]=0.f; sB[3]=0.f;
    #pragma unroll
    for (int c = 0; c < 4; ++c) {
        const int rA = li, rB = li + 16;
        bf16x8 kfA = *(const bf16x8*)(Kl + ((rA * 256 + c * 64 + g16 * 16) ^ ((rA & 7) << 4)));
        bf16x8 kfB = *(const bf16x8*)(Kl + ((rB * 256 + c * 64 + g16 * 16) ^ ((rB & 7) << 4)));
        sA = __builtin_amdgcn_mfma_f32_16x16x32_bf16(S.qf[c], kfA, sA, 0, 0, 0);
        sB = __builtin_amdgcn_mfma_f32_16x16x32_bf16(S.qf[c], kfB, sB, 0, 0, 0);
    }
    float pA[4], pB[4], corr[4];
    #pragma unroll
    for (int r = 0; r < 4; ++r) {
        const int qrow = qt * 16 + g16 * 4 + r;
        float a  = (k0 + li      <= qrow) ? sA[r] * SCALE_F : NEGINF;
        float bb = (k0 + 16 + li <= qrow) ? sB[r] * SCALE_F : NEGINF;
        float rm = fmaxf(a, bb);
        #pragma unroll
        for (int off = 1; off < 16; off <<= 1) rm = fmaxf(rm, __shfl_xor(rm, off));
        const float mn = fmaxf(S.mrow[r], rm);
        corr[r] = __expf(S.mrow[r] - mn);
        pA[r] = __expf(a  - mn);
        pB[r] = __expf(bb - mn);
        float rs = pA[r] + pB[r];
        #pragma unroll
        for (int off = 1; off < 16; off <<= 1) rs += __shfl_xor(rs, off);
        S.lsum[r] = S.lsum[r] * corr[r] + rs;
        S.mrow[r] = mn;
    }
    #pragma unroll
    for (int n = 0; n < 8; ++n)
        #pragma unroll
        for (int r = 0; r < 4; ++r) S.o[n][r] *= corr[r];

    #pragma unroll
    for (int r = 0; r < 4; ++r) {
        const int row = g16 * 4 + r;
        const int xo  = (row & 3) << 4;
        *(short*)(pbase + ((row * 64 + li * 2     ) ^ xo)) = f2bf(pA[r]);
        *(short*)(pbase + ((row * 64 + 32 + li * 2) ^ xo)) = f2bf(pB[r]);
    }
    asm volatile("s_waitcnt lgkmcnt(0)" ::: "memory");
    __builtin_amdgcn_sched_barrier(0);
    bf16x8 pa = *(const bf16x8*)(pbase + ((li * 64 + g16 * 16) ^ ((li & 3) << 4)));

    #pragma unroll
    for (int n = 0; n < 8; ++n) {
        bf16x8 vf = *(const bf16x8*)(Vt2 + (n * 1024 + g16 * 256 + li * 16));
        S.o[n] = __builtin_amdgcn_mfma_f32_16x16x32_bf16(pa, vf, S.o[n], 0, 0, 0);
    }
}

__device__ __forceinline__ void qs_out(QS& S, int qt, int b, int h, int g16, int li,
                                       float* __restrict__ out) {
    float inv[4];
    #pragma unroll
    for (int r = 0; r < 4; ++r) inv[r] = 1.f / S.lsum[r];
    #pragma unroll
    for (int n = 0; n < 8; ++n) {
        #pragma unroll
        for (int r = 0; r < 4; ++r) {
            const int t = b * FLEN + qt * 16 + g16 * 4 + r;
            out[(long)t * 4096 + h * DD + n * 16 + li] = S.o[n][r] * inv[r];
        }
    }
}

__global__ __launch_bounds__(512, 2)
void fill_kernel(const float* __restrict__ q, const float* __restrict__ k,
                 const float* __restrict__ v, float* __restrict__ out)
{
    __shared__ short Kl[32 * 128];
    __shared__ short Vt2[8 * 4 * 16 * 8];
    __shared__ short plds[8][16][32];

    const int bid = blockIdx.x;
    const int b   = bid >> 6;
    const int h   = (bid >> 1) & 31;
    const int jh  = bid & 1;
    const int tid  = threadIdx.x;
    const int wv   = tid >> 6;
    const int lane = tid & 63;
    const int g16  = lane >> 4;
    const int li   = lane & 15;

    const int qtA = 2 * wv + jh;
    const int qtB = qtA + 16;
    const int npA = wv + 1;
    const int npB = wv + 9;

    QS SA, SB2;
    qs_init(SA,  q + ((long)(b * FLEN + qtA * 16 + li) * HH + h) * DD, g16);
    qs_init(SB2, q + ((long)(b * FLEN + qtB * 16 + li) * HH + h) * DD, g16);

    const int spos = tid >> 4;
    const int sd8  = tid & 15;
    const int vd   = tid & 127;
    const int voct = tid >> 7;

    char* pbase = (char*)&plds[wv][0][0];

    for (int kp = 0; kp < 16; ++kp) {
        const int k0 = kp * 32;
        {
            const float* src = k + ((long)(b * FLEN + k0 + spos) * HH + h) * DD + sd8 * 8;
            bf16x8 w = load8_bf16(src);
            const int base = spos * 256 + sd8 * 16;
            *(bf16x8*)((char*)Kl + (base ^ ((spos & 7) << 4))) = w;
        }
        {
            const float* src = v + ((long)(b * FLEN + k0 + voct * 8) * HH + h) * DD + vd;
            bf16x8 w;
            #pragma unroll
            for (int jj = 0; jj < 8; ++jj)
                w[jj] = f2bf(src[(long)jj * HD]);
            *(bf16x8*)((char*)Vt2 + ((vd >> 4) * 1024 + voct * 256 + (vd & 15) * 16)) = w;
        }
        __syncthreads();

        if (kp < npA) qs_tile(SA,  qtA, k0, (const char*)Kl, (const char*)Vt2, pbase, g16, li);
        if (kp < npB) qs_tile(SB2, qtB, k0, (const char*)Kl, (const char*)Vt2, pbase, g16, li);

        __syncthreads();
    }

    qs_out(SA,  qtA, b, h, g16, li, out);
    qs_out(SB2, qtB, b, h, g16, li, out);
}

extern "C" void kernel_launch(void* const* d_in, const int* in_sizes, int n_in,
                              void* d_out, int out_size, void* d_ws, size_t ws_size,
                              hipStream_t stream) {
    const float* q  = (const float*)d_in[0];
    const float* k  = (const float*)d_in[1];
    const float* v  = (const float*)d_in[2];
    const float* kc = (const float*)d_in[3];
    const float* vc = (const float*)d_in[4];
    // d_in[5] = slot_mapping (derivable; caches are not outputs)
    const int* btab    = (const int*)d_in[6];
    const int* ctxlens = (const int*)d_in[7];
    float* outp = (float*)d_out;
    float* ws   = (float*)d_ws;   // 16384 partial records x 136 floats = 8.9 MB

    gen_kernel  <<<dim3(512), dim3(256), 0, stream>>>(q, k, v, kc, vc, btab, ctxlens, ws);
    merge_kernel<<<dim3(256), dim3(256), 0, stream>>>(ws, outp);
    fill_kernel <<<dim3(256), dim3(512), 0, stream>>>(q, k, v, outp);
}

// Round 15
// 163.670 us; speedup vs baseline: 1.4980x; 1.2329x over previous
//
#include <hip/hip_runtime.h>
#include <hip/hip_bf16.h>

#define HH 32
#define DD 128
#define HD (HH*DD)          // 4096
#define NFILL 2048
#define FLEN 512
#define SCALE_F 0.08838834764831845f
#define NEGINF (-1e30f)
#define PSTRIDE 136         // floats per partial record: [m, l, pad..., acc[128]]

typedef short bf16x8 __attribute__((ext_vector_type(8)));
typedef float f32x4 __attribute__((ext_vector_type(4)));

__device__ __forceinline__ short f2bf(float x) {
    union { float f; unsigned u; } c; c.f = x;
    unsigned u = c.u;
    u += 0x7FFFu + ((u >> 16) & 1u);   // RNE
    return (short)(u >> 16);
}

__device__ __forceinline__ bf16x8 load8_bf16(const float* __restrict__ p) {
    float4 a = *(const float4*)p;
    float4 b = *(const float4*)(p + 4);
    bf16x8 r;
    r[0]=f2bf(a.x); r[1]=f2bf(a.y); r[2]=f2bf(a.z); r[3]=f2bf(a.w);
    r[4]=f2bf(b.x); r[5]=f2bf(b.y); r[6]=f2bf(b.z); r[7]=f2bf(b.w);
    return r;
}

// ======================= GEN (r9 structure + NON-TEMPORAL K/V reads) =======================
// 1024 blocks x 256 thr: g=bid>>6, h=(bid>>1)&31, half=bid&1.
// 4 waves x 128 positions; 16-lane group per position, 4 pos/group-iter.
// K/V cache reads are nontemporal (zero reuse, 536MB stream > L3): no cache allocation.
__global__ __launch_bounds__(256)
void gen_kernel(const float* __restrict__ q, const float* __restrict__ k,
                const float* __restrict__ v, const float* __restrict__ kc,
                const float* __restrict__ vc, const int* __restrict__ btab,
                const int* __restrict__ ctxlens, float* __restrict__ ws)
{
    __shared__ int sblk[64];
    __shared__ float accs[16][DD];
    __shared__ float marr[16], larr[16];

    const int bid  = blockIdx.x;
    const int g    = bid >> 6;
    const int h    = (bid >> 1) & 31;
    const int half = bid & 1;
    const int wv   = threadIdx.x >> 6;
    const int lane = threadIdx.x & 63;
    const int g16  = lane >> 4;
    const int li   = lane & 15;
    const int ctx  = ctxlens[g];

    if (threadIdx.x < 64) sblk[threadIdx.x] = btab[g * 64 + threadIdx.x];
    __syncthreads();

    const long qoff = (long)(NFILL + g) * HD + h * DD;
    float qr[8];
    {
        float4 a  = *(const float4*)(q + qoff + li * 8);
        float4 b2 = *(const float4*)(q + qoff + li * 8 + 4);
        qr[0]=a.x; qr[1]=a.y; qr[2]=a.z; qr[3]=a.w;
        qr[4]=b2.x; qr[5]=b2.y; qr[6]=b2.z; qr[7]=b2.w;
    }

    float m = NEGINF, l = 0.f;
    float o[8];
    #pragma unroll
    for (int j = 0; j < 8; ++j) o[j] = 0.f;

    const int wbase = half * 512 + wv * 128;

    #pragma unroll 1
    for (int c = 0; c < 8; ++c) {
        const int pb = wbase + c * 16 + g16 * 4;
        f32x4 ka[4][2], va[4][2];
        #pragma unroll
        for (int i = 0; i < 4; ++i) {
            const int p = pb + i;
            const float* kb; const float* vb;
            if (p == ctx - 1) {            // fresh token lives in k/v, not cache
                kb = k + qoff; vb = v + qoff;
            } else {
                const int slot = sblk[p >> 4] * 16 + (p & 15);
                kb = kc + (long)slot * HD + h * DD;
                vb = vc + (long)slot * HD + h * DD;
            }
            ka[i][0] = __builtin_nontemporal_load((const f32x4*)(kb + li * 8));
            ka[i][1] = __builtin_nontemporal_load((const f32x4*)(kb + li * 8 + 4));
            va[i][0] = __builtin_nontemporal_load((const f32x4*)(vb + li * 8));
            va[i][1] = __builtin_nontemporal_load((const f32x4*)(vb + li * 8 + 4));
        }
        float s[4];
        #pragma unroll
        for (int i = 0; i < 4; ++i) {
            float d0 = ka[i][0][0]*qr[0] + ka[i][0][1]*qr[1] + ka[i][0][2]*qr[2] + ka[i][0][3]*qr[3]
                     + ka[i][1][0]*qr[4] + ka[i][1][1]*qr[5] + ka[i][1][2]*qr[6] + ka[i][1][3]*qr[7];
            d0 += __shfl_xor(d0, 1);
            d0 += __shfl_xor(d0, 2);
            d0 += __shfl_xor(d0, 4);
            d0 += __shfl_xor(d0, 8);
            s[i] = d0 * SCALE_F;
        }
        const float mn = fmaxf(m, fmaxf(fmaxf(s[0], s[1]), fmaxf(s[2], s[3])));
        const float sc = __expf(m - mn);
        const float p0 = __expf(s[0] - mn);
        const float p1 = __expf(s[1] - mn);
        const float p2 = __expf(s[2] - mn);
        const float p3 = __expf(s[3] - mn);
        l = l * sc + (p0 + p1 + p2 + p3);
        #pragma unroll
        for (int j = 0; j < 4; ++j) {
            o[j] = o[j]*sc + p0*va[0][0][j] + p1*va[1][0][j]
                           + p2*va[2][0][j] + p3*va[3][0][j];
            o[j+4] = o[j+4]*sc + p0*va[0][1][j] + p1*va[1][1][j]
                               + p2*va[2][1][j] + p3*va[3][1][j];
        }
        m = mn;
    }

    const int pid = wv * 4 + g16;
    #pragma unroll
    for (int j = 0; j < 8; ++j) accs[pid][li * 8 + j] = o[j];
    if (li == 0) { marr[pid] = m; larr[pid] = l; }
    __syncthreads();

    if (threadIdx.x < DD) {
        const int d = threadIdx.x;
        float M = NEGINF;
        #pragma unroll
        for (int t = 0; t < 16; ++t) M = fmaxf(M, marr[t]);
        float L = 0.f, a = 0.f;
        #pragma unroll
        for (int t = 0; t < 16; ++t) {
            const float cc = __expf(marr[t] - M);
            L += cc * larr[t];
            a += cc * accs[t][d];
        }
        const long base = (long)(((g * 32 + h) * 2) + half) * PSTRIDE;
        ws[base + 8 + d] = a;
        if (d == 0) { ws[base] = M; ws[base + 1] = L; }
    }
}

// ======================= MERGE (r9, unchanged) =======================
__global__ __launch_bounds__(256)
void merge_kernel(const float* __restrict__ ws, float* __restrict__ out)
{
    const int idx = blockIdx.x * 256 + threadIdx.x;
    const int gh  = idx >> 7;
    const int d   = idx & 127;
    const int g   = gh >> 5;
    const int h   = gh & 31;
    const long b0 = (long)gh * 2 * PSTRIDE;
    const long b1 = b0 + PSTRIDE;
    const float m0 = ws[b0], l0 = ws[b0 + 1];
    const float m1 = ws[b1], l1 = ws[b1 + 1];
    const float M  = fmaxf(m0, m1);
    const float e0 = __expf(m0 - M), e1 = __expf(m1 - M);
    const float num = e0 * ws[b0 + 8 + d] + e1 * ws[b1 + 8 + d];
    const float den = e0 * l0 + e1 * l1;
    out[(long)(NFILL + g) * 4096 + h * DD + d] = num / den;
}

// ======================= FILL v4 (r9 known-good, unchanged) =======================
struct QS {
    bf16x8 qf[4];
    float  mrow[4], lsum[4];
    f32x4  o[8];
};

__device__ __forceinline__ void qs_init(QS& S, const float* qbase, int g16) {
    #pragma unroll
    for (int c = 0; c < 4; ++c) S.qf[c] = load8_bf16(qbase + c * 32 + g16 * 8);
    #pragma unroll
    for (int r = 0; r < 4; ++r) { S.mrow[r] = NEGINF; S.lsum[r] = 0.f; }
    #pragma unroll
    for (int n = 0; n < 8; ++n) { S.o[n][0]=0.f; S.o[n][1]=0.f; S.o[n][2]=0.f; S.o[n][3]=0.f; }
}

__device__ __forceinline__ void qs_tile(QS& S, int qt, int k0,
                                        const char* Kl, const char* Vt2,
                                        char* pbase, int g16, int li) {
    f32x4 sA; sA[0]=0.f; sA[1]=0.f; sA[2]=0.f; sA[3]=0.f;
    f32x4 sB; sB[0]=0.f; sB[1]=0.f; sB[2]=0.f; sB[3]=0.f;
    #pragma unroll
    for (int c = 0; c < 4; ++c) {
        const int rA = li, rB = li + 16;
        bf16x8 kfA = *(const bf16x8*)(Kl + ((rA * 256 + c * 64 + g16 * 16) ^ ((rA & 7) << 4)));
        bf16x8 kfB = *(const bf16x8*)(Kl + ((rB * 256 + c * 64 + g16 * 16) ^ ((rB & 7) << 4)));
        sA = __builtin_amdgcn_mfma_f32_16x16x32_bf16(S.qf[c], kfA, sA, 0, 0, 0);
        sB = __builtin_amdgcn_mfma_f32_16x16x32_bf16(S.qf[c], kfB, sB, 0, 0, 0);
    }
    float pA[4], pB[4], corr[4];
    #pragma unroll
    for (int r = 0; r < 4; ++r) {
        const int qrow = qt * 16 + g16 * 4 + r;
        float a  = (k0 + li      <= qrow) ? sA[r] * SCALE_F : NEGINF;
        float bb = (k0 + 16 + li <= qrow) ? sB[r] * SCALE_F : NEGINF;
        float rm = fmaxf(a, bb);
        #pragma unroll
        for (int off = 1; off < 16; off <<= 1) rm = fmaxf(rm, __shfl_xor(rm, off));
        const float mn = fmaxf(S.mrow[r], rm);
        corr[r] = __expf(S.mrow[r] - mn);
        pA[r] = __expf(a  - mn);
        pB[r] = __expf(bb - mn);
        float rs = pA[r] + pB[r];
        #pragma unroll
        for (int off = 1; off < 16; off <<= 1) rs += __shfl_xor(rs, off);
        S.lsum[r] = S.lsum[r] * corr[r] + rs;
        S.mrow[r] = mn;
    }
    #pragma unroll
    for (int n = 0; n < 8; ++n)
        #pragma unroll
        for (int r = 0; r < 4; ++r) S.o[n][r] *= corr[r];

    #pragma unroll
    for (int r = 0; r < 4; ++r) {
        const int row = g16 * 4 + r;
        const int xo  = (row & 3) << 4;
        *(short*)(pbase + ((row * 64 + li * 2     ) ^ xo)) = f2bf(pA[r]);
        *(short*)(pbase + ((row * 64 + 32 + li * 2) ^ xo)) = f2bf(pB[r]);
    }
    asm volatile("s_waitcnt lgkmcnt(0)" ::: "memory");
    __builtin_amdgcn_sched_barrier(0);
    bf16x8 pa = *(const bf16x8*)(pbase + ((li * 64 + g16 * 16) ^ ((li & 3) << 4)));

    #pragma unroll
    for (int n = 0; n < 8; ++n) {
        bf16x8 vf = *(const bf16x8*)(Vt2 + (n * 1024 + g16 * 256 + li * 16));
        S.o[n] = __builtin_amdgcn_mfma_f32_16x16x32_bf16(pa, vf, S.o[n], 0, 0, 0);
    }
}

__device__ __forceinline__ void qs_out(QS& S, int qt, int b, int h, int g16, int li,
                                       float* __restrict__ out) {
    float inv[4];
    #pragma unroll
    for (int r = 0; r < 4; ++r) inv[r] = 1.f / S.lsum[r];
    #pragma unroll
    for (int n = 0; n < 8; ++n) {
        #pragma unroll
        for (int r = 0; r < 4; ++r) {
            const int t = b * FLEN + qt * 16 + g16 * 4 + r;
            out[(long)t * 4096 + h * DD + n * 16 + li] = S.o[n][r] * inv[r];
        }
    }
}

__global__ __launch_bounds__(512, 2)
void fill_kernel(const float* __restrict__ q, const float* __restrict__ k,
                 const float* __restrict__ v, float* __restrict__ out)
{
    __shared__ short Kl[32 * 128];
    __shared__ short Vt2[8 * 4 * 16 * 8];
    __shared__ short plds[8][16][32];

    const int bid = blockIdx.x;
    const int b   = bid >> 6;
    const int h   = (bid >> 1) & 31;
    const int jh  = bid & 1;
    const int tid  = threadIdx.x;
    const int wv   = tid >> 6;
    const int lane = tid & 63;
    const int g16  = lane >> 4;
    const int li   = lane & 15;

    const int qtA = 2 * wv + jh;
    const int qtB = qtA + 16;
    const int npA = wv + 1;
    const int npB = wv + 9;

    QS SA, SB2;
    qs_init(SA,  q + ((long)(b * FLEN + qtA * 16 + li) * HH + h) * DD, g16);
    qs_init(SB2, q + ((long)(b * FLEN + qtB * 16 + li) * HH + h) * DD, g16);

    const int spos = tid >> 4;
    const int sd8  = tid & 15;
    const int vd   = tid & 127;
    const int voct = tid >> 7;

    char* pbase = (char*)&plds[wv][0][0];

    for (int kp = 0; kp < 16; ++kp) {
        const int k0 = kp * 32;
        {
            const float* src = k + ((long)(b * FLEN + k0 + spos) * HH + h) * DD + sd8 * 8;
            bf16x8 w = load8_bf16(src);
            const int base = spos * 256 + sd8 * 16;
            *(bf16x8*)((char*)Kl + (base ^ ((spos & 7) << 4))) = w;
        }
        {
            const float* src = v + ((long)(b * FLEN + k0 + voct * 8) * HH + h) * DD + vd;
            bf16x8 w;
            #pragma unroll
            for (int jj = 0; jj < 8; ++jj)
                w[jj] = f2bf(src[(long)jj * HD]);
            *(bf16x8*)((char*)Vt2 + ((vd >> 4) * 1024 + voct * 256 + (vd & 15) * 16)) = w;
        }
        __syncthreads();

        if (kp < npA) qs_tile(SA,  qtA, k0, (const char*)Kl, (const char*)Vt2, pbase, g16, li);
        if (kp < npB) qs_tile(SB2, qtB, k0, (const char*)Kl, (const char*)Vt2, pbase, g16, li);

        __syncthreads();
    }

    qs_out(SA,  qtA, b, h, g16, li, out);
    qs_out(SB2, qtB, b, h, g16, li, out);
}

extern "C" void kernel_launch(void* const* d_in, const int* in_sizes, int n_in,
                              void* d_out, int out_size, void* d_ws, size_t ws_size,
                              hipStream_t stream) {
    const float* q  = (const float*)d_in[0];
    const float* k  = (const float*)d_in[1];
    const float* v  = (const float*)d_in[2];
    const float* kc = (const float*)d_in[3];
    const float* vc = (const float*)d_in[4];
    // d_in[5] = slot_mapping (derivable; caches are not outputs)
    const int* btab    = (const int*)d_in[6];
    const int* ctxlens = (const int*)d_in[7];
    float* outp = (float*)d_out;
    float* ws   = (float*)d_ws;   // 1024 partials x 136 floats = 557 KB

    gen_kernel  <<<dim3(1024), dim3(256), 0, stream>>>(q, k, v, kc, vc, btab, ctxlens, ws);
    merge_kernel<<<dim3(256),  dim3(256), 0, stream>>>(ws, outp);
    fill_kernel <<<dim3(256),  dim3(512), 0, stream>>>(q, k, v, outp);
}